// Round 6
// baseline (106.757 us; speedup 1.0000x reference)
//
#include <hip/hip_runtime.h>
#include <math.h>

// Problem constants (fixed by the reference).
#define M_PTS 16384
#define N_PTS 16384

// Spatial binning: 42x42 cells of h=0.25 over [-5.25, 5.25).
// Drop terms with exp2(arg) < 2^-TCUT <=> sq > TCUT/cmag (r_cut^2).
// ell=0.1 -> cmag=72.13 -> r_cut=0.527 -> K=3 rows, disc-shaped col ranges.
// Planner falls back to full scans if ell too large for the grid.
#define NC 42
#define NCELLS (NC * NC)          // 1764
#define H 0.25f
#define INV_H 4.0f
#define ORIG (-5.25f)
#define TCUT 20.0f
#define KMAX 7
#define MAXROWS 16
#define NPAIRT (M_PTS / 128)      // 128 test groups of 128 sorted points
#define CHUNK 1024
#define MAX_ITEMS 2048            // worst case: NPAIRT * 16 full chunks
#define GMAIN_GRID 512            // grid-stride over items (~380 typical)

// ws byte offsets
#define OFF_NITEMS 0
#define OFF_HTR   64
#define OFF_HTE   (OFF_HTR + NCELLS * 4)
#define OFF_ZEND  (OFF_HTE + NCELLS * 4)              // memset [0, OFF_ZEND)
#define OFF_SROW  (OFF_ZEND + 64)                     // int[NPAIRT*MAXROWS]
#define OFF_SPRE  (OFF_SROW + NPAIRT * MAXROWS * 4)   // int[NPAIRT*(MAXROWS+1)]
#define OFF_ITEMS (OFF_SPRE + NPAIRT * (MAXROWS + 1) * 4)
#define OFF_RKT   ((OFF_ITEMS + MAX_ITEMS * 4 + 255) & ~255)
#define OFF_RKE   (OFF_RKT + N_PTS * 4)
#define OFF_TRA   ((OFF_RKE + N_PTS * 4 + 255) & ~255)
#define OFF_TRW1  (OFF_TRA + N_PTS * 16)
#define OFF_T4    (OFF_TRW1 + N_PTS * 4)
#define WS_NEED   (OFF_T4 + (size_t)M_PTS * 16)       // ~700 KB

__device__ __forceinline__ float fexp2(float x) {
#if __has_builtin(__builtin_amdgcn_exp2f)
    return __builtin_amdgcn_exp2f(x);
#else
    return exp2f(x);
#endif
}

__device__ __forceinline__ void gatomic_fadd(float* p, float v) {
    asm volatile("global_atomic_add_f32 %0, %1, off" :: "v"(p), "v"(v) : "memory");
}

__device__ __forceinline__ int cellco(float v) {
    int c = (int)floorf((v - ORIG) * INV_H);
    return min(NC - 1, max(0, c));
}

// --- d1: whole-grid histogram + per-point rank capture + out zero ------------
// 256 blocks x 64 threads: the per-thread chain is two dependent L2-atomic
// round-trips (pure latency), so engage as many CUs as possible.
__global__ __launch_bounds__(64) void hist_kernel(
        const float2* __restrict__ Xtr, const float2* __restrict__ Xte,
        int* __restrict__ histTr, int* __restrict__ histTe,
        int* __restrict__ rkT, int* __restrict__ rkE,
        float2* __restrict__ out2) {
    int i = blockIdx.x * 64 + threadIdx.x;
    if (i >= N_PTS) return;
    out2[i] = make_float2(0.f, 0.f);
    float2 t = Xtr[i];
    float2 x = Xte[i];
    rkT[i] = atomicAdd(&histTr[cellco(t.y) * NC + cellco(t.x)], 1);
    rkE[i] = atomicAdd(&histTe[cellco(x.y) * NC + cellco(x.x)], 1);
}

// --- d2: fused scan + scatter + (block 0) planner ----------------------------
// Every block redundantly scans both 1764-int histograms (L2-warm, 14 KB) in
// LDS (8 cells/thread via two int4 loads), then scatters its 256 points
// atomic-free via precomputed ranks. Block 0's first 2 waves additionally run
// the item planner, overlapped with the other blocks' scatter.
__global__ __launch_bounds__(256) void planscatter_kernel(
        const float2* __restrict__ Xtr, const float2* __restrict__ Xte,
        const float2* __restrict__ alpha,
        const float* __restrict__ log_ell, const float* __restrict__ log_sf,
        const int* __restrict__ histTr, const int* __restrict__ histTe,
        const int* __restrict__ rkT, const int* __restrict__ rkE,
        float4* __restrict__ trA, float* __restrict__ trW1,
        float4* __restrict__ T4,
        int* __restrict__ sRowG, int* __restrict__ sPreG,
        int* __restrict__ items, int* __restrict__ nitemsG) {
    __shared__ int trsL[NCELLS + 1], PL[NCELLS + 1];
    __shared__ int wtot[4];
    const int tid = threadIdx.x;
    const int lane = tid & 63;
    const int wid = tid >> 6;

    // dual sequential exclusive scans, 8 cells/thread (2048 >= 1764)
#pragma unroll
    for (int a = 0; a < 2; ++a) {
        const int* __restrict__ h = a ? histTe : histTr;
        int* __restrict__ s = a ? PL : trsL;
        const int c0 = tid * 8;
        int v[8];
        if (c0 + 7 < NCELLS) {
            int4 u0 = *(const int4*)&h[c0];
            int4 u1 = *(const int4*)&h[c0 + 4];
            v[0] = u0.x; v[1] = u0.y; v[2] = u0.z; v[3] = u0.w;
            v[4] = u1.x; v[5] = u1.y; v[6] = u1.z; v[7] = u1.w;
        } else {
#pragma unroll
            for (int k = 0; k < 8; ++k)
                v[k] = (c0 + k < NCELLS) ? h[c0 + k] : 0;
        }
        int lo[8];
        int sum = 0;
#pragma unroll
        for (int k = 0; k < 8; ++k) { lo[k] = sum; sum += v[k]; }
        int inc = sum;
#pragma unroll
        for (int d = 1; d < 64; d <<= 1) {
            int u = __shfl_up(inc, d, 64);
            if (lane >= d) inc += u;
        }
        if (lane == 63) wtot[wid] = inc;
        __syncthreads();
        int base = 0;
        for (int w = 0; w < wid; ++w) base += wtot[w];
        int ex = base + inc - sum;
#pragma unroll
        for (int k = 0; k < 8; ++k) {
            int c = c0 + k;
            if (c < NCELLS) s[c] = ex + lo[k];
        }
        if (tid == 0) s[NCELLS] = N_PTS;
        __syncthreads();
    }

    // scatter this block's 256 points (atomic-free; bases from LDS scans)
    {
        int i = blockIdx.x * 256 + tid;
        float ell = expf(log_ell[0]);
        float sf2 = expf(2.0f * log_sf[0]);
        float c = -0.5f / (ell * ell) * 1.4426950408889634f;  // * log2(e), c < 0

        float2 t = Xtr[i];
        float2 a = alpha[i];
        int ct = cellco(t.y) * NC + cellco(t.x);
        int pt = trsL[ct] + rkT[i];
        trA[pt] = make_float4(-2.f * c * t.x, -2.f * c * t.y,
                              c * (t.x * t.x + t.y * t.y), sf2 * a.x);
        trW1[pt] = sf2 * a.y;

        float2 x = Xte[i];
        int cx = cellco(x.y) * NC + cellco(x.x);
        int px = PL[cx] + rkE[i];
        T4[px] = make_float4(x.x, x.y, c * (x.x * x.x + x.y * x.y),
                             __int_as_float(i));
    }

    // planner: block 0 only, one thread per 128-point sorted test group
    if (blockIdx.x == 0 && tid < NPAIRT) {
        const int w = tid;
        const float ell = expf(log_ell[0]);
        const float cmag = 0.5f / (ell * ell) * 1.4426950408889634f;
        const float r2 = TCUT / cmag;
        const int K = (int)floorf(sqrtf(r2) * INV_H) + 1;

        // cells containing sorted test positions 128w and 128w+127
        int clo, chi;
        {
            int s = w * 128, lo = 0, hi = NCELLS;
            while (lo + 1 < hi) { int m = (lo + hi) >> 1; if (PL[m] <= s) lo = m; else hi = m; }
            clo = lo;
            s = w * 128 + 127; lo = 0; hi = NCELLS;
            while (lo + 1 < hi) { int m = (lo + hi) >> 1; if (PL[m] <= s) lo = m; else hi = m; }
            chi = lo;
        }
        const int rl = clo / NC, cl = clo % NC;
        const int rh = chi / NC, ch = chi % NC;
        int wlo = max(0, rl - K), whi = min(NC - 1, rh + K);
        int nr = whi - wlo + 1;
        bool full = (K > KMAX) || (nr > MAXROWS);

        int prw = 0;
        if (full) {
            sRowG[w * MAXROWS] = 0;
            sPreG[w * (MAXROWS + 1)] = 0;
            prw = N_PTS;
            for (int i = 1; i <= MAXROWS; ++i) sPreG[w * (MAXROWS + 1) + i] = N_PTS;
        } else {
            const bool single = (rl == rh);
            const int cmin = single ? cl : 0;
            const int cmax = single ? ch : (NC - 1);
            sPreG[w * (MAXROWS + 1)] = 0;
            int idx = 0;
            for (int wr = wlo; wr <= whi; ++wr, ++idx) {
                int dy = (wr < rl) ? (rl - wr) : ((wr > rh) ? (wr - rh) : 0);
                int kx;
                if (dy <= 1) kx = K;
                else {
                    float d = (float)(dy - 1) * H;
                    kx = (int)floorf(sqrtf(fmaxf(r2 - d * d, 0.f)) * INV_H) + 1;
                }
                int c0 = max(0, cmin - kx);
                int c1 = min(NC - 1, cmax + kx);
                int js = trsL[wr * NC + c0];
                int je = trsL[wr * NC + c1 + 1];
                sRowG[w * MAXROWS + idx] = js - prw;   // j = gg + offset
                prw += je - js;
                sPreG[w * (MAXROWS + 1) + idx + 1] = prw;
            }
            for (; idx < MAXROWS; ++idx)
                sPreG[w * (MAXROWS + 1) + idx + 1] = prw;
        }
        const int nch = (prw + CHUNK - 1) / CHUNK;
        for (int k = 0; k < nch; ++k) {
            int slot = atomicAdd(nitemsG, 1);
            items[slot] = w | (k << 16);
        }
    }
}

// --- d3: main kernel ---------------------------------------------------------
// Item = (test-pair pr of 128 sorted points, 1024-train chunk k). Block = 512
// threads = 8 waves; each lane owns TWO test points (lane, lane+64 of the
// pair) -> the 5 LDS broadcast reads per quad amortize over 8 pairs. 8 waves
// split the quads; tail chunks only compute ceil(n/4) quads (padded to x16).
// Epilogue split: wave 0 reduces+writes the A test points, wave 1 the B ones.
// Grid-stride over items.
__global__ __launch_bounds__(512) void gp_main(
        const float4* __restrict__ T4, const float4* __restrict__ trA,
        const float* __restrict__ trW1, const int* __restrict__ sRowG,
        const int* __restrict__ sPreG, const int* __restrict__ items,
        const int* __restrict__ nitemsG, float* __restrict__ out) {
    const int nit = nitemsG[0];

    __shared__ float4 sA[CHUNK];                     // 16 KB
    __shared__ __align__(16) float sW[CHUNK];        // 4 KB
    __shared__ float2 redA[8][64];                   // 4 KB
    __shared__ float2 redB[8][64];                   // 4 KB
    __shared__ int off[MAXROWS];
    __shared__ int pre[MAXROWS + 1];

    const int tid = threadIdx.x;
    const int p = tid >> 6;          // wave 0..7
    const int lane = tid & 63;

    for (int ib = (int)blockIdx.x; ib < nit; ib += GMAIN_GRID) {
        const int item = items[ib];
        const int pr = item & 0xFFFF;
        const int k = item >> 16;

        if (tid < MAXROWS) off[tid] = sRowG[pr * MAXROWS + tid];
        if (tid < MAXROWS + 1) pre[tid] = sPreG[pr * (MAXROWS + 1) + tid];

        float4 tpA = T4[pr * 128 + lane];
        float4 tpB = T4[pr * 128 + 64 + lane];
        const float xA = tpA.x, yA = tpA.y, bA = tpA.z;
        const float xB = tpB.x, yB = tpB.y, bB = tpB.z;
        const int oiA = __float_as_int(tpA.w);
        const int oiB = __float_as_int(tpB.w);
        __syncthreads();

        const int total = pre[MAXROWS];
        const int base0 = k << 10;
        const int n = min(CHUNK, total - base0);
        const int nP = (n + 15) & ~15;   // staged slots (pad to x16)
        const int nq = nP >> 2;          // quads to compute

        // stage: persistent row cursor (gg monotone across the strided loop)
        {
            int r = 0;
            for (int g = tid; g < nP; g += 512) {
                float4 tv; float wv;
                if (g < n) {
                    int gg = base0 + g;
                    while (gg >= pre[r + 1]) ++r;
                    int j = gg + off[r];
                    tv = trA[j];
                    wv = trW1[j];
                } else {
                    tv = make_float4(0.f, 0.f, -1.0e30f, 0.f);
                    wv = 0.f;
                }
                sA[g] = tv;
                sW[g] = wv;
            }
        }
        __syncthreads();

        float a0 = 0.f, a1 = 0.f, c0 = 0.f, c1 = 0.f;
#pragma unroll 2
        for (int q = p; q < nq; q += 8) {
            float4 t0 = sA[4 * q];
            float4 t1 = sA[4 * q + 1];
            float4 t2 = sA[4 * q + 2];
            float4 t3 = sA[4 * q + 3];
            float4 wv = *(const float4*)&sW[4 * q];
            float e0 = fexp2(fmaf(t0.x, xA, fmaf(t0.y, yA, bA + t0.z)));
            float e1 = fexp2(fmaf(t1.x, xA, fmaf(t1.y, yA, bA + t1.z)));
            float e2 = fexp2(fmaf(t2.x, xA, fmaf(t2.y, yA, bA + t2.z)));
            float e3 = fexp2(fmaf(t3.x, xA, fmaf(t3.y, yA, bA + t3.z)));
            a0 = fmaf(e0, t0.w, a0); a1 = fmaf(e0, wv.x, a1);
            a0 = fmaf(e1, t1.w, a0); a1 = fmaf(e1, wv.y, a1);
            a0 = fmaf(e2, t2.w, a0); a1 = fmaf(e2, wv.z, a1);
            a0 = fmaf(e3, t3.w, a0); a1 = fmaf(e3, wv.w, a1);
            float f0 = fexp2(fmaf(t0.x, xB, fmaf(t0.y, yB, bB + t0.z)));
            float f1 = fexp2(fmaf(t1.x, xB, fmaf(t1.y, yB, bB + t1.z)));
            float f2 = fexp2(fmaf(t2.x, xB, fmaf(t2.y, yB, bB + t2.z)));
            float f3 = fexp2(fmaf(t3.x, xB, fmaf(t3.y, yB, bB + t3.z)));
            c0 = fmaf(f0, t0.w, c0); c1 = fmaf(f0, wv.x, c1);
            c0 = fmaf(f1, t1.w, c0); c1 = fmaf(f1, wv.y, c1);
            c0 = fmaf(f2, t2.w, c0); c1 = fmaf(f2, wv.z, c1);
            c0 = fmaf(f3, t3.w, c0); c1 = fmaf(f3, wv.w, c1);
        }

        redA[p][lane] = make_float2(a0, a1);
        redB[p][lane] = make_float2(c0, c1);
        __syncthreads();
        if (p == 0) {
            float s0 = 0.f, s1 = 0.f;
#pragma unroll
            for (int q = 0; q < 8; ++q) {
                float2 v = redA[q][lane];
                s0 += v.x; s1 += v.y;
            }
            if (s0 != 0.f || s1 != 0.f) {
                gatomic_fadd(&out[2 * oiA], s0);
                gatomic_fadd(&out[2 * oiA + 1], s1);
            }
        } else if (p == 1) {
            float s0 = 0.f, s1 = 0.f;
#pragma unroll
            for (int q = 0; q < 8; ++q) {
                float2 v = redB[q][lane];
                s0 += v.x; s1 += v.y;
            }
            if (s0 != 0.f || s1 != 0.f) {
                gatomic_fadd(&out[2 * oiB], s0);
                gatomic_fadd(&out[2 * oiB + 1], s1);
            }
        }
        __syncthreads();   // protect off/pre/sA/red before next item
    }
}

// --- dense fallback (ws too small) ------------------------------------------
__global__ __launch_bounds__(256, 8) void gp_dense(
        const float2* __restrict__ Xte, const float2* __restrict__ Xtr,
        const float2* __restrict__ alpha, const float* __restrict__ log_ell,
        const float* __restrict__ log_sf, float* __restrict__ out) {
    __shared__ float4 sSt[128];
    __shared__ float sA1[128];
    const int tid = threadIdx.x;
    const float ell = expf(log_ell[0]);
    const float c = -0.5f / (ell * ell) * 1.4426950408889634f;
    const int j0 = blockIdx.y * 128;
    if (tid < 128) {
        const float sf2 = expf(2.0f * log_sf[0]);
        float2 t = Xtr[j0 + tid];
        float2 a = alpha[j0 + tid];
        sSt[tid] = make_float4(-2.f * c * t.x, -2.f * c * t.y,
                               c * (t.x * t.x + t.y * t.y), sf2 * a.x);
        sA1[tid] = sf2 * a.y;
    }
    const int base = blockIdx.x * 1024 + tid;
    float2 x0 = Xte[base], x1 = Xte[base + 256];
    float2 x2 = Xte[base + 512], x3 = Xte[base + 768];
    const float b0 = c * (x0.x * x0.x + x0.y * x0.y);
    const float b1 = c * (x1.x * x1.x + x1.y * x1.y);
    const float b2 = c * (x2.x * x2.x + x2.y * x2.y);
    const float b3 = c * (x3.x * x3.x + x3.y * x3.y);
    __syncthreads();
    float a00 = 0.f, a01 = 0.f, a10 = 0.f, a11 = 0.f;
    float a20 = 0.f, a21 = 0.f, a30 = 0.f, a31 = 0.f;
#pragma unroll 2
    for (int j = 0; j < 128; ++j) {
        float4 s = sSt[j];
        float w1 = sA1[j];
        float e0 = fexp2(fminf(fmaf(s.x, x0.x, fmaf(s.y, x0.y, b0 + s.z)), 0.f));
        float e1 = fexp2(fminf(fmaf(s.x, x1.x, fmaf(s.y, x1.y, b1 + s.z)), 0.f));
        float e2 = fexp2(fminf(fmaf(s.x, x2.x, fmaf(s.y, x2.y, b2 + s.z)), 0.f));
        float e3 = fexp2(fminf(fmaf(s.x, x3.x, fmaf(s.y, x3.y, b3 + s.z)), 0.f));
        a00 = fmaf(e0, s.w, a00); a01 = fmaf(e0, w1, a01);
        a10 = fmaf(e1, s.w, a10); a11 = fmaf(e1, w1, a11);
        a20 = fmaf(e2, s.w, a20); a21 = fmaf(e2, w1, a21);
        a30 = fmaf(e3, s.w, a30); a31 = fmaf(e3, w1, a31);
    }
    gatomic_fadd(&out[2 * base], a00);            gatomic_fadd(&out[2 * base + 1], a01);
    gatomic_fadd(&out[2 * (base + 256)], a10);    gatomic_fadd(&out[2 * (base + 256) + 1], a11);
    gatomic_fadd(&out[2 * (base + 512)], a20);    gatomic_fadd(&out[2 * (base + 512) + 1], a21);
    gatomic_fadd(&out[2 * (base + 768)], a30);    gatomic_fadd(&out[2 * (base + 768) + 1], a31);
}

extern "C" void kernel_launch(void* const* d_in, const int* in_sizes, int n_in,
                              void* d_out, int out_size, void* d_ws, size_t ws_size,
                              hipStream_t stream) {
    const float2* Xte = (const float2*)d_in[0];
    const float2* Xtr = (const float2*)d_in[1];
    const float2* alpha = (const float2*)d_in[2];
    const float* log_ell = (const float*)d_in[3];
    const float* log_sf = (const float*)d_in[4];
    float* out = (float*)d_out;

    if (ws_size >= WS_NEED) {
        char* ws = (char*)d_ws;
        int* nitems = (int*)(ws + OFF_NITEMS);
        int* histTr = (int*)(ws + OFF_HTR);
        int* histTe = (int*)(ws + OFF_HTE);
        int* sRowG = (int*)(ws + OFF_SROW);
        int* sPreG = (int*)(ws + OFF_SPRE);
        int* items = (int*)(ws + OFF_ITEMS);
        int* rkT   = (int*)(ws + OFF_RKT);
        int* rkE   = (int*)(ws + OFF_RKE);
        float4* trA = (float4*)(ws + OFF_TRA);
        float* trW1 = (float*)(ws + OFF_TRW1);
        float4* T4 = (float4*)(ws + OFF_T4);

        hipMemsetAsync(ws, 0, OFF_ZEND, stream);   // nitems + both histograms
        hist_kernel<<<N_PTS / 64, 64, 0, stream>>>(
            Xtr, Xte, histTr, histTe, rkT, rkE, (float2*)out);
        planscatter_kernel<<<N_PTS / 256, 256, 0, stream>>>(
            Xtr, Xte, alpha, log_ell, log_sf, histTr, histTe, rkT, rkE,
            trA, trW1, T4, sRowG, sPreG, items, nitems);
        gp_main<<<GMAIN_GRID, 512, 0, stream>>>(T4, trA, trW1, sRowG, sPreG,
                                                items, nitems, out);
    } else {
        hipMemsetAsync(out, 0, (size_t)out_size * sizeof(float), stream);
        dim3 grid(M_PTS / 1024, N_PTS / 128);
        gp_dense<<<grid, 256, 0, stream>>>(Xte, Xtr, alpha, log_ell, log_sf, out);
    }
}

// Round 7
// 105.096 us; speedup vs baseline: 1.0158x; 1.0158x over previous
//
#include <hip/hip_runtime.h>
#include <math.h>

// Problem constants (fixed by the reference).
#define M_PTS 16384
#define N_PTS 16384

// Spatial binning: 42x42 cells of h=0.25 over [-5.25, 5.25).
// Drop terms with exp2(arg) < 2^-TCUT <=> sq > TCUT/cmag (r_cut^2).
// ell=0.1 -> cmag=72.13 -> r_cut=0.527 -> K=3 rows, disc-shaped col ranges.
// Planner falls back to full scans if ell too large for the grid.
#define NC 42
#define NCELLS (NC * NC)          // 1764
#define H 0.25f
#define INV_H 4.0f
#define ORIG (-5.25f)
#define TCUT 20.0f
#define KMAX 7
#define MAXROWS 16
#define NPAIRT (M_PTS / 128)      // 128 test groups of 128 sorted points
#define CHUNK 1024
#define MAX_ITEMS 2048            // worst case: NPAIRT * 16 full chunks
#define GMAIN_GRID 1024           // grid-stride over items

// ws byte offsets
#define OFF_NITEMS 0
#define OFF_HTR   64
#define OFF_HTE   (OFF_HTR + NCELLS * 4)
#define OFF_ZEND  (OFF_HTE + NCELLS * 4)              // memset [0, OFF_ZEND)
#define OFF_SROW  (OFF_ZEND + 64)                     // int[NPAIRT*MAXROWS]
#define OFF_SPRE  (OFF_SROW + NPAIRT * MAXROWS * 4)   // int[NPAIRT*(MAXROWS+1)]
#define OFF_ITEMS (OFF_SPRE + NPAIRT * (MAXROWS + 1) * 4)
#define OFF_RKT   ((OFF_ITEMS + MAX_ITEMS * 4 + 255) & ~255)
#define OFF_RKE   (OFF_RKT + N_PTS * 4)
#define OFF_TRA   ((OFF_RKE + N_PTS * 4 + 255) & ~255)
#define OFF_TRW1  (OFF_TRA + N_PTS * 16)
#define OFF_T4    (OFF_TRW1 + N_PTS * 4)
#define WS_NEED   (OFF_T4 + (size_t)M_PTS * 16)       // ~700 KB

__device__ __forceinline__ float fexp2(float x) {
#if __has_builtin(__builtin_amdgcn_exp2f)
    return __builtin_amdgcn_exp2f(x);
#else
    return exp2f(x);
#endif
}

__device__ __forceinline__ void gatomic_fadd(float* p, float v) {
    asm volatile("global_atomic_add_f32 %0, %1, off" :: "v"(p), "v"(v) : "memory");
}

__device__ __forceinline__ int cellco(float v) {
    int c = (int)floorf((v - ORIG) * INV_H);
    return min(NC - 1, max(0, c));
}

// --- d1: whole-grid histogram + per-point rank capture + out zero ------------
// 256 blocks x 64 threads: the per-thread chain is two dependent L2-atomic
// round-trips (pure latency), so engage as many CUs as possible.
__global__ __launch_bounds__(64) void hist_kernel(
        const float2* __restrict__ Xtr, const float2* __restrict__ Xte,
        int* __restrict__ histTr, int* __restrict__ histTe,
        int* __restrict__ rkT, int* __restrict__ rkE,
        float2* __restrict__ out2) {
    int i = blockIdx.x * 64 + threadIdx.x;
    if (i >= N_PTS) return;
    out2[i] = make_float2(0.f, 0.f);
    float2 t = Xtr[i];
    float2 x = Xte[i];
    rkT[i] = atomicAdd(&histTr[cellco(t.y) * NC + cellco(t.x)], 1);
    rkE[i] = atomicAdd(&histTe[cellco(x.y) * NC + cellco(x.x)], 1);
}

// --- d2: fused scan + scatter + (block 0) planner ----------------------------
// Every block redundantly scans both 1764-int histograms (L2-warm, 14 KB) in
// LDS, then scatters its 256 points atomic-free via precomputed ranks.
// Block 0's first 2 waves additionally run the item planner, overlapped with
// the other blocks' scatter.
__global__ __launch_bounds__(256) void planscatter_kernel(
        const float2* __restrict__ Xtr, const float2* __restrict__ Xte,
        const float2* __restrict__ alpha,
        const float* __restrict__ log_ell, const float* __restrict__ log_sf,
        const int* __restrict__ histTr, const int* __restrict__ histTe,
        const int* __restrict__ rkT, const int* __restrict__ rkE,
        float4* __restrict__ trA, float* __restrict__ trW1,
        float4* __restrict__ T4,
        int* __restrict__ sRowG, int* __restrict__ sPreG,
        int* __restrict__ items, int* __restrict__ nitemsG) {
    __shared__ int trsL[NCELLS + 1], PL[NCELLS + 1];
    __shared__ int wtot[4];
    const int tid = threadIdx.x;
    const int lane = tid & 63;
    const int wid = tid >> 6;

    // dual sequential exclusive scans, 256 threads x 7 cells each (1792 >= 1764)
#pragma unroll
    for (int a = 0; a < 2; ++a) {
        const int* __restrict__ h = a ? histTe : histTr;
        int* __restrict__ s = a ? PL : trsL;
        int lo[7];
        int sum = 0;
#pragma unroll
        for (int k = 0; k < 7; ++k) {
            int c = tid * 7 + k;
            int v = (c < NCELLS) ? h[c] : 0;
            lo[k] = sum; sum += v;
        }
        int inc = sum;
#pragma unroll
        for (int d = 1; d < 64; d <<= 1) {
            int u = __shfl_up(inc, d, 64);
            if (lane >= d) inc += u;
        }
        if (lane == 63) wtot[wid] = inc;
        __syncthreads();
        int base = 0;
        for (int w = 0; w < wid; ++w) base += wtot[w];
        int ex = base + inc - sum;
#pragma unroll
        for (int k = 0; k < 7; ++k) {
            int c = tid * 7 + k;
            if (c < NCELLS) s[c] = ex + lo[k];
        }
        if (tid == 0) s[NCELLS] = N_PTS;
        __syncthreads();
    }

    // scatter this block's 256 points (atomic-free; bases from LDS scans)
    {
        int i = blockIdx.x * 256 + tid;
        float ell = expf(log_ell[0]);
        float sf2 = expf(2.0f * log_sf[0]);
        float c = -0.5f / (ell * ell) * 1.4426950408889634f;  // * log2(e), c < 0

        float2 t = Xtr[i];
        float2 a = alpha[i];
        int ct = cellco(t.y) * NC + cellco(t.x);
        int pt = trsL[ct] + rkT[i];
        trA[pt] = make_float4(-2.f * c * t.x, -2.f * c * t.y,
                              c * (t.x * t.x + t.y * t.y), sf2 * a.x);
        trW1[pt] = sf2 * a.y;

        float2 x = Xte[i];
        int cx = cellco(x.y) * NC + cellco(x.x);
        int px = PL[cx] + rkE[i];
        T4[px] = make_float4(x.x, x.y, c * (x.x * x.x + x.y * x.y),
                             __int_as_float(i));
    }

    // planner: block 0 only, one thread per 128-point sorted test group
    if (blockIdx.x == 0 && tid < NPAIRT) {
        const int w = tid;
        const float ell = expf(log_ell[0]);
        const float cmag = 0.5f / (ell * ell) * 1.4426950408889634f;
        const float r2 = TCUT / cmag;
        const int K = (int)floorf(sqrtf(r2) * INV_H) + 1;

        // cells containing sorted test positions 128w and 128w+127
        int clo, chi;
        {
            int s = w * 128, lo = 0, hi = NCELLS;
            while (lo + 1 < hi) { int m = (lo + hi) >> 1; if (PL[m] <= s) lo = m; else hi = m; }
            clo = lo;
            s = w * 128 + 127; lo = 0; hi = NCELLS;
            while (lo + 1 < hi) { int m = (lo + hi) >> 1; if (PL[m] <= s) lo = m; else hi = m; }
            chi = lo;
        }
        const int rl = clo / NC, cl = clo % NC;
        const int rh = chi / NC, ch = chi % NC;
        int wlo = max(0, rl - K), whi = min(NC - 1, rh + K);
        int nr = whi - wlo + 1;
        bool full = (K > KMAX) || (nr > MAXROWS);

        int prw = 0;
        if (full) {
            sRowG[w * MAXROWS] = 0;
            sPreG[w * (MAXROWS + 1)] = 0;
            prw = N_PTS;
            for (int i = 1; i <= MAXROWS; ++i) sPreG[w * (MAXROWS + 1) + i] = N_PTS;
        } else {
            const bool single = (rl == rh);
            const int cmin = single ? cl : 0;
            const int cmax = single ? ch : (NC - 1);
            sPreG[w * (MAXROWS + 1)] = 0;
            int idx = 0;
            for (int wr = wlo; wr <= whi; ++wr, ++idx) {
                int dy = (wr < rl) ? (rl - wr) : ((wr > rh) ? (wr - rh) : 0);
                int kx;
                if (dy <= 1) kx = K;
                else {
                    float d = (float)(dy - 1) * H;
                    kx = (int)floorf(sqrtf(fmaxf(r2 - d * d, 0.f)) * INV_H) + 1;
                }
                int c0 = max(0, cmin - kx);
                int c1 = min(NC - 1, cmax + kx);
                int js = trsL[wr * NC + c0];
                int je = trsL[wr * NC + c1 + 1];
                sRowG[w * MAXROWS + idx] = js - prw;   // j = gg + offset
                prw += je - js;
                sPreG[w * (MAXROWS + 1) + idx + 1] = prw;
            }
            for (; idx < MAXROWS; ++idx)
                sPreG[w * (MAXROWS + 1) + idx + 1] = prw;
        }
        const int nch = (prw + CHUNK - 1) / CHUNK;
        for (int k = 0; k < nch; ++k) {
            int slot = atomicAdd(nitemsG, 1);
            items[slot] = w | (k << 16);
        }
    }
}

// --- d3: main kernel ---------------------------------------------------------
// Item = (test-pair pr of 128 sorted points, 1024-train chunk k). Block = 512
// threads = 8 waves; each lane owns TWO test points (lane, lane+64 of the
// pair) -> the 5 LDS broadcast reads per quad amortize over 8 pairs. 8 waves
// split the quads (halves the per-item critical path vs 4 waves: items <<
// blocks, so gp_main's wall-clock IS one item's duration). Tail chunks only
// compute ceil(n/4) quads (padded to x16), not the full CHUNK. Grid-stride
// over items; LDS-reduce; 4 atomics per lane in wave 0.
__global__ __launch_bounds__(512) void gp_main(
        const float4* __restrict__ T4, const float4* __restrict__ trA,
        const float* __restrict__ trW1, const int* __restrict__ sRowG,
        const int* __restrict__ sPreG, const int* __restrict__ items,
        const int* __restrict__ nitemsG, float* __restrict__ out) {
    const int nit = nitemsG[0];

    __shared__ float4 sA[CHUNK];                     // 16 KB
    __shared__ __align__(16) float sW[CHUNK];        // 4 KB
    __shared__ float4 red[8][64];                    // 8 KB
    __shared__ int off[MAXROWS];
    __shared__ int pre[MAXROWS + 1];

    const int tid = threadIdx.x;
    const int p = tid >> 6;          // wave 0..7
    const int lane = tid & 63;

    for (int ib = (int)blockIdx.x; ib < nit; ib += GMAIN_GRID) {
        const int item = items[ib];
        const int pr = item & 0xFFFF;
        const int k = item >> 16;

        if (tid < MAXROWS) off[tid] = sRowG[pr * MAXROWS + tid];
        if (tid < MAXROWS + 1) pre[tid] = sPreG[pr * (MAXROWS + 1) + tid];

        float4 tpA = T4[pr * 128 + lane];
        float4 tpB = T4[pr * 128 + 64 + lane];
        const float xA = tpA.x, yA = tpA.y, bA = tpA.z;
        const float xB = tpB.x, yB = tpB.y, bB = tpB.z;
        const int oiA = __float_as_int(tpA.w);
        const int oiB = __float_as_int(tpB.w);
        __syncthreads();

        const int total = pre[MAXROWS];
        const int base0 = k << 10;
        const int n = min(CHUNK, total - base0);
        const int nP = (n + 15) & ~15;   // staged slots (pad to x16)
        const int nq = nP >> 2;          // quads to compute

        // stage: persistent row cursor (gg monotone across the strided loop)
        {
            int r = 0;
            for (int g = tid; g < nP; g += 512) {
                float4 tv; float wv;
                if (g < n) {
                    int gg = base0 + g;
                    while (gg >= pre[r + 1]) ++r;
                    int j = gg + off[r];
                    tv = trA[j];
                    wv = trW1[j];
                } else {
                    tv = make_float4(0.f, 0.f, -1.0e30f, 0.f);
                    wv = 0.f;
                }
                sA[g] = tv;
                sW[g] = wv;
            }
        }
        __syncthreads();

        float a0 = 0.f, a1 = 0.f, c0 = 0.f, c1 = 0.f;
#pragma unroll 2
        for (int q = p; q < nq; q += 8) {
            float4 t0 = sA[4 * q];
            float4 t1 = sA[4 * q + 1];
            float4 t2 = sA[4 * q + 2];
            float4 t3 = sA[4 * q + 3];
            float4 wv = *(const float4*)&sW[4 * q];
            float e0 = fexp2(fmaf(t0.x, xA, fmaf(t0.y, yA, bA + t0.z)));
            float e1 = fexp2(fmaf(t1.x, xA, fmaf(t1.y, yA, bA + t1.z)));
            float e2 = fexp2(fmaf(t2.x, xA, fmaf(t2.y, yA, bA + t2.z)));
            float e3 = fexp2(fmaf(t3.x, xA, fmaf(t3.y, yA, bA + t3.z)));
            a0 = fmaf(e0, t0.w, a0); a1 = fmaf(e0, wv.x, a1);
            a0 = fmaf(e1, t1.w, a0); a1 = fmaf(e1, wv.y, a1);
            a0 = fmaf(e2, t2.w, a0); a1 = fmaf(e2, wv.z, a1);
            a0 = fmaf(e3, t3.w, a0); a1 = fmaf(e3, wv.w, a1);
            float f0 = fexp2(fmaf(t0.x, xB, fmaf(t0.y, yB, bB + t0.z)));
            float f1 = fexp2(fmaf(t1.x, xB, fmaf(t1.y, yB, bB + t1.z)));
            float f2 = fexp2(fmaf(t2.x, xB, fmaf(t2.y, yB, bB + t2.z)));
            float f3 = fexp2(fmaf(t3.x, xB, fmaf(t3.y, yB, bB + t3.z)));
            c0 = fmaf(f0, t0.w, c0); c1 = fmaf(f0, wv.x, c1);
            c0 = fmaf(f1, t1.w, c0); c1 = fmaf(f1, wv.y, c1);
            c0 = fmaf(f2, t2.w, c0); c1 = fmaf(f2, wv.z, c1);
            c0 = fmaf(f3, t3.w, c0); c1 = fmaf(f3, wv.w, c1);
        }

        red[p][lane] = make_float4(a0, a1, c0, c1);
        __syncthreads();
        if (p == 0) {
            float4 s = red[0][lane];
#pragma unroll
            for (int q = 1; q < 8; ++q) {
                float4 v = red[q][lane];
                s.x += v.x; s.y += v.y; s.z += v.z; s.w += v.w;
            }
            if (s.x != 0.f || s.y != 0.f) {
                gatomic_fadd(&out[2 * oiA], s.x);
                gatomic_fadd(&out[2 * oiA + 1], s.y);
            }
            if (s.z != 0.f || s.w != 0.f) {
                gatomic_fadd(&out[2 * oiB], s.z);
                gatomic_fadd(&out[2 * oiB + 1], s.w);
            }
        }
        __syncthreads();   // protect off/pre/sA before next item
    }
}

// --- dense fallback (ws too small) ------------------------------------------
__global__ __launch_bounds__(256, 8) void gp_dense(
        const float2* __restrict__ Xte, const float2* __restrict__ Xtr,
        const float2* __restrict__ alpha, const float* __restrict__ log_ell,
        const float* __restrict__ log_sf, float* __restrict__ out) {
    __shared__ float4 sSt[128];
    __shared__ float sA1[128];
    const int tid = threadIdx.x;
    const float ell = expf(log_ell[0]);
    const float c = -0.5f / (ell * ell) * 1.4426950408889634f;
    const int j0 = blockIdx.y * 128;
    if (tid < 128) {
        const float sf2 = expf(2.0f * log_sf[0]);
        float2 t = Xtr[j0 + tid];
        float2 a = alpha[j0 + tid];
        sSt[tid] = make_float4(-2.f * c * t.x, -2.f * c * t.y,
                               c * (t.x * t.x + t.y * t.y), sf2 * a.x);
        sA1[tid] = sf2 * a.y;
    }
    const int base = blockIdx.x * 1024 + tid;
    float2 x0 = Xte[base], x1 = Xte[base + 256];
    float2 x2 = Xte[base + 512], x3 = Xte[base + 768];
    const float b0 = c * (x0.x * x0.x + x0.y * x0.y);
    const float b1 = c * (x1.x * x1.x + x1.y * x1.y);
    const float b2 = c * (x2.x * x2.x + x2.y * x2.y);
    const float b3 = c * (x3.x * x3.x + x3.y * x3.y);
    __syncthreads();
    float a00 = 0.f, a01 = 0.f, a10 = 0.f, a11 = 0.f;
    float a20 = 0.f, a21 = 0.f, a30 = 0.f, a31 = 0.f;
#pragma unroll 2
    for (int j = 0; j < 128; ++j) {
        float4 s = sSt[j];
        float w1 = sA1[j];
        float e0 = fexp2(fminf(fmaf(s.x, x0.x, fmaf(s.y, x0.y, b0 + s.z)), 0.f));
        float e1 = fexp2(fminf(fmaf(s.x, x1.x, fmaf(s.y, x1.y, b1 + s.z)), 0.f));
        float e2 = fexp2(fminf(fmaf(s.x, x2.x, fmaf(s.y, x2.y, b2 + s.z)), 0.f));
        float e3 = fexp2(fminf(fmaf(s.x, x3.x, fmaf(s.y, x3.y, b3 + s.z)), 0.f));
        a00 = fmaf(e0, s.w, a00); a01 = fmaf(e0, w1, a01);
        a10 = fmaf(e1, s.w, a10); a11 = fmaf(e1, w1, a11);
        a20 = fmaf(e2, s.w, a20); a21 = fmaf(e2, w1, a21);
        a30 = fmaf(e3, s.w, a30); a31 = fmaf(e3, w1, a31);
    }
    gatomic_fadd(&out[2 * base], a00);            gatomic_fadd(&out[2 * base + 1], a01);
    gatomic_fadd(&out[2 * (base + 256)], a10);    gatomic_fadd(&out[2 * (base + 256) + 1], a11);
    gatomic_fadd(&out[2 * (base + 512)], a20);    gatomic_fadd(&out[2 * (base + 512) + 1], a21);
    gatomic_fadd(&out[2 * (base + 768)], a30);    gatomic_fadd(&out[2 * (base + 768) + 1], a31);
}

extern "C" void kernel_launch(void* const* d_in, const int* in_sizes, int n_in,
                              void* d_out, int out_size, void* d_ws, size_t ws_size,
                              hipStream_t stream) {
    const float2* Xte = (const float2*)d_in[0];
    const float2* Xtr = (const float2*)d_in[1];
    const float2* alpha = (const float2*)d_in[2];
    const float* log_ell = (const float*)d_in[3];
    const float* log_sf = (const float*)d_in[4];
    float* out = (float*)d_out;

    if (ws_size >= WS_NEED) {
        char* ws = (char*)d_ws;
        int* nitems = (int*)(ws + OFF_NITEMS);
        int* histTr = (int*)(ws + OFF_HTR);
        int* histTe = (int*)(ws + OFF_HTE);
        int* sRowG = (int*)(ws + OFF_SROW);
        int* sPreG = (int*)(ws + OFF_SPRE);
        int* items = (int*)(ws + OFF_ITEMS);
        int* rkT   = (int*)(ws + OFF_RKT);
        int* rkE   = (int*)(ws + OFF_RKE);
        float4* trA = (float4*)(ws + OFF_TRA);
        float* trW1 = (float*)(ws + OFF_TRW1);
        float4* T4 = (float4*)(ws + OFF_T4);

        hipMemsetAsync(ws, 0, OFF_ZEND, stream);   // nitems + both histograms
        hist_kernel<<<N_PTS / 64, 64, 0, stream>>>(
            Xtr, Xte, histTr, histTe, rkT, rkE, (float2*)out);
        planscatter_kernel<<<N_PTS / 256, 256, 0, stream>>>(
            Xtr, Xte, alpha, log_ell, log_sf, histTr, histTe, rkT, rkE,
            trA, trW1, T4, sRowG, sPreG, items, nitems);
        gp_main<<<GMAIN_GRID, 512, 0, stream>>>(T4, trA, trW1, sRowG, sPreG,
                                                items, nitems, out);
    } else {
        hipMemsetAsync(out, 0, (size_t)out_size * sizeof(float), stream);
        dim3 grid(M_PTS / 1024, N_PTS / 128);
        gp_dense<<<grid, 256, 0, stream>>>(Xte, Xtr, alpha, log_ell, log_sf, out);
    }
}